// Round 8
// baseline (2676.944 us; speedup 1.0000x reference)
//
#include <hip/hip_runtime.h>

#define B_ 64
#define T_ 512
#define I_ 256
#define H_ 1024
#define O_ 256

#define NCLUST 4
#define WPC 32        // workgroups per cluster (each owns 32 h-rows)
#define MB 16         // batches per cluster
#define ROWS 32       // h-rows per WG (2 MFMA n-tiles)
#define SENT 0x7FFF7FFFu   // f16 NaN pair: tanh output can never equal this

typedef _Float16 f16;
typedef _Float16 f16x2 __attribute__((ext_vector_type(2)));
typedef _Float16 f16x4 __attribute__((ext_vector_type(4)));
typedef _Float16 half8 __attribute__((ext_vector_type(8)));
typedef float floatx4 __attribute__((ext_vector_type(4)));
typedef unsigned int uint4v __attribute__((ext_vector_type(4)));

// ---------- memory helpers ----------
// sc0 sc1: bypass L1+L2, access MALL (device coherence point) — always correct
__device__ __forceinline__ uint4v load_uc16(const void* p) {
  uint4v r;
  asm volatile("global_load_dwordx4 %0, %1, off sc0 sc1" : "=v"(r) : "v"(p));
  return r;
}
__device__ __forceinline__ void store_uc4(void* p, unsigned v) {
  asm volatile("global_store_dword %0, %1, off sc0 sc1" :: "v"(p), "v"(v) : "memory");
}
__device__ __forceinline__ void store_uc16(void* p, uint4v v) {
  asm volatile("global_store_dwordx4 %0, %1, off sc0 sc1" :: "v"(p), "v"(v) : "memory");
}
// sc0 only: bypass L1, served by this XCD's L2 — fast path (opportunistic)
__device__ __forceinline__ uint4v load_l2_16(const void* p) {
  uint4v r;
  asm volatile("global_load_dwordx4 %0, %1, off sc0" : "=v"(r) : "v"(p));
  return r;
}
__device__ __forceinline__ void store_l2_4(void* p, unsigned v) {
  asm volatile("global_store_dword %0, %1, off sc0" :: "v"(p), "v"(v) : "memory");
}
// dual store: L2 (fast, same-XCD consumers) + MALL (guaranteed fallback)
__device__ __forceinline__ void store_dual(void* p, unsigned v) {
  store_l2_4(p, v);
  store_uc4(p, v);
}
__device__ __forceinline__ unsigned pack_f16x2(float a, float b) {
  f16x2 t; t[0] = (f16)a; t[1] = (f16)b;
  return __builtin_bit_cast(unsigned, t);
}

#if __has_builtin(__builtin_amdgcn_fdot2)
__device__ __forceinline__ float dot2f(f16x2 a, f16x2 b, float c) {
  return __builtin_amdgcn_fdot2(a, b, c, false);
}
#else
__device__ __forceinline__ float dot2f(f16x2 a, f16x2 b, float c) {
  return fmaf((float)a[0], (float)b[0], fmaf((float)a[1], (float)b[1], c));
}
#endif

__device__ __forceinline__ float dot8f(half8 w, half8 v, float acc) {
  acc = dot2f(__builtin_shufflevector(w, w, 0, 1), __builtin_shufflevector(v, v, 0, 1), acc);
  acc = dot2f(__builtin_shufflevector(w, w, 2, 3), __builtin_shufflevector(v, v, 2, 3), acc);
  acc = dot2f(__builtin_shufflevector(w, w, 4, 5), __builtin_shufflevector(v, v, 4, 5), acc);
  acc = dot2f(__builtin_shufflevector(w, w, 6, 7), __builtin_shufflevector(v, v, 6, 7), acc);
  return acc;
}

// ---------- converters / init ----------
__global__ void cast_f16(const float* __restrict__ src, f16* __restrict__ dst, int n4) {
  int i = blockIdx.x * blockDim.x + threadIdx.x;
  if (i >= n4) return;
  float4 a = reinterpret_cast<const float4*>(src)[i];
  f16x4 v;
  v[0] = (f16)a.x; v[1] = (f16)a.y; v[2] = (f16)a.z; v[3] = (f16)a.w;
  reinterpret_cast<f16x4*>(dst)[i] = v;
}

__global__ void convert_T8(const float* __restrict__ src, f16* __restrict__ dst,
                           int R, int K) {
  int K8 = K >> 3;
  int total = R * K8;
  int idx = blockIdx.x * blockDim.x + threadIdx.x;
  if (idx >= total) return;
  int r = idx / K8;
  int k8 = idx - r * K8;
  const float4* s = reinterpret_cast<const float4*>(src + (size_t)r * K + (size_t)k8 * 8);
  float4 a = s[0], b = s[1];
  half8 v;
  v[0] = (f16)a.x; v[1] = (f16)a.y; v[2] = (f16)a.z; v[3] = (f16)a.w;
  v[4] = (f16)b.x; v[5] = (f16)b.y; v[6] = (f16)b.z; v[7] = (f16)b.w;
  reinterpret_cast<half8*>(dst)[(size_t)k8 * R + r] = v;
}

// sentinel-fill hseq via MALL bypass stores; re-run every launch (replay-safe)
__global__ void init_hseq(unsigned* __restrict__ p, long n16) {
  uint4v sv; sv[0] = SENT; sv[1] = SENT; sv[2] = SENT; sv[3] = SENT;
  long i = (long)blockIdx.x * blockDim.x + threadIdx.x;
  const long stride = (long)gridDim.x * blockDim.x;
  for (; i < n16; i += stride) store_uc16(p + 4 * i, sv);
}

// ---------- tier-1 recurrent kernel: sentinel dataflow, dual-store, 2-phase poll ----------
// grid 256 x 256 thr. Cluster c = wg&7 (only c<4 work; others exit) owns batches
// [c*16,+16). Worker w = wg>>3 (0..31) owns h rows [w*32,+32). Under round-robin
// dispatch, cluster c's 32 WGs all land on XCD c -> sc0 (L2) exchange hits; if
// placement differs, the MALL phase (rounds >=2) is the r6-proven protocol.
// Producer: dual-store h (sc0 + sc0sc1), fire-and-forget (data IS the flag).
// Consumer wave wv: its 8 h-packets map 1:1 to producers w'=wv*8+i; selective
// per-packet retry; 2 rounds via L2 then MALL.
__global__ __launch_bounds__(256) void rnn8(
    const f16* __restrict__ whh,   // [H][H] f16
    const f16* __restrict__ wih,   // [H][I] f16
    const f16* __restrict__ xbf,   // [B][T][I] f16
    const float* __restrict__ bih,
    const float* __restrict__ bhh,
    f16* __restrict__ hseq) {      // [T][NCLUST][MB][H] f16 (sentinel-filled)
  const int wg = blockIdx.x;
  const int c = wg & 7;
  if (c >= NCLUST) return;        // uniform exit: XCDs 4..7 idle by design
  const int w = wg >> 3;          // 0..31
  const int tid = threadIdx.x;
  const int wv = tid >> 6;
  const int lane = tid & 63;
  const int lr = lane & 15;
  const int kb = lane >> 4;
  const int n0 = w * ROWS;
  const int b0 = c * MB;

  // stationary B-fragments: 2 n-tiles x (8 h + 2 x) K-chunks
  half8 bfh0[8], bfh1[8], bfx0[2], bfx1[2];
#pragma unroll
  for (int i = 0; i < 8; ++i) {
    const int k = wv * 256 + i * 32 + kb * 8;
    bfh0[i] = *reinterpret_cast<const half8*>(&whh[(size_t)(n0 + lr) * H_ + k]);
    bfh1[i] = *reinterpret_cast<const half8*>(&whh[(size_t)(n0 + 16 + lr) * H_ + k]);
  }
#pragma unroll
  for (int j = 0; j < 2; ++j) {
    const int k = wv * 64 + j * 32 + kb * 8;
    bfx0[j] = *reinterpret_cast<const half8*>(&wih[(size_t)(n0 + lr) * I_ + k]);
    bfx1[j] = *reinterpret_cast<const half8*>(&wih[(size_t)(n0 + 16 + lr) * I_ + k]);
  }

  // output ownership after K-split reduce (validated): m=((lane>>4)<<2)|wv, col=lane&15
  const int m = ((lane >> 4) << 2) | wv;
  const int nl = lane & 15;
  const float bias0 = bih[n0 + nl] + bhh[n0 + nl];
  const float bias1 = bih[n0 + 16 + nl] + bhh[n0 + 16 + nl];

  const f16* xrow = xbf + (size_t)(b0 + lr) * T_ * I_ + wv * 64 + kb * 8;

  __shared__ floatx4 red[2][2][4][64];   // [parity][ntile][wave][lane], 16 KB
  const size_t CST = (size_t)NCLUST * MB * H_;
  const size_t coff = (size_t)c * MB * H_;

  for (int s = 1; s <= T_; ++s) {
    const f16* xs = xrow + (size_t)(s - 1) * I_;
    half8 ax0 = *reinterpret_cast<const half8*>(xs);
    half8 ax1 = *reinterpret_cast<const half8*>(xs + 32);

    floatx4 p0 = {0.f,0.f,0.f,0.f}, p1 = {0.f,0.f,0.f,0.f};
    floatx4 q0 = {0.f,0.f,0.f,0.f}, q1 = {0.f,0.f,0.f,0.f};
    p0 = __builtin_amdgcn_mfma_f32_16x16x32_f16(ax0, bfx0[0], p0, 0, 0, 0);
    p1 = __builtin_amdgcn_mfma_f32_16x16x32_f16(ax1, bfx0[1], p1, 0, 0, 0);
    q0 = __builtin_amdgcn_mfma_f32_16x16x32_f16(ax0, bfx1[0], q0, 0, 0, 0);
    q1 = __builtin_amdgcn_mfma_f32_16x16x32_f16(ax1, bfx1[1], q1, 0, 0, 0);

    if (s > 1) {
      const f16* hr = hseq + (size_t)(s - 2) * CST + coff;  // h[s-1]
      uint4v af[8];
      unsigned need = 0xFFu;
      int g = 0;
      for (;;) {
#pragma unroll
        for (int i = 0; i < 8; ++i) {
          if (need & (1u << i)) {
            const f16* p = &hr[(size_t)lr * H_ + wv * 256 + i * 32 + kb * 8];
            if (g < 2) af[i] = load_l2_16(p);   // fast path: own-XCD L2
            else       af[i] = load_uc16(p);    // guaranteed path: MALL
          }
        }
        asm volatile("s_waitcnt vmcnt(0)" ::: "memory");
        unsigned nn = 0u;
#pragma unroll
        for (int i = 0; i < 8; ++i) {
          if (need & (1u << i)) {
            unsigned bad = (unsigned)(af[i][0] == SENT) | (unsigned)(af[i][1] == SENT) |
                           (unsigned)(af[i][2] == SENT) | (unsigned)(af[i][3] == SENT);
            nn |= bad << i;
          }
        }
        need = nn;
        if (__all(need == 0u)) break;
        if (++g > (1 << 12)) break;   // fail-fast valve (validation catches)
        __builtin_amdgcn_s_sleep(1);
      }
      __builtin_amdgcn_sched_barrier(0);
#pragma unroll
      for (int i = 0; i < 8; ++i) {
        half8 a = __builtin_bit_cast(half8, af[i]);
        if (i & 1) {
          p1 = __builtin_amdgcn_mfma_f32_16x16x32_f16(a, bfh0[i], p1, 0, 0, 0);
          q1 = __builtin_amdgcn_mfma_f32_16x16x32_f16(a, bfh1[i], q1, 0, 0, 0);
        } else {
          p0 = __builtin_amdgcn_mfma_f32_16x16x32_f16(a, bfh0[i], p0, 0, 0, 0);
          q0 = __builtin_amdgcn_mfma_f32_16x16x32_f16(a, bfh1[i], q0, 0, 0, 0);
        }
      }
    }

    const int pr = s & 1;
    red[pr][0][wv][lane] = p0 + p1;
    red[pr][1][wv][lane] = q0 + q1;
    __syncthreads();

    f16* hw = hseq + (size_t)(s - 1) * CST + coff;
    {
      float v0 = red[pr][0][0][lane][wv] + red[pr][0][1][lane][wv] +
                 red[pr][0][2][lane][wv] + red[pr][0][3][lane][wv] + bias0;
      float h0v = tanhf(v0);
      float po0 = __shfl_xor(h0v, 1);
      float v1 = red[pr][1][0][lane][wv] + red[pr][1][1][lane][wv] +
                 red[pr][1][2][lane][wv] + red[pr][1][3][lane][wv] + bias1;
      float h1v = tanhf(v1);
      float po1 = __shfl_xor(h1v, 1);
      if (!(lane & 1)) {
        store_dual(&hw[(size_t)m * H_ + n0 + nl], pack_f16x2(h0v, po0));
        store_dual(&hw[(size_t)m * H_ + n0 + 16 + nl], pack_f16x2(h1v, po1));
      }
    }
    // fire-and-forget: data IS the flag.
  }
}

// FC head over flat h_last rows: row b at hlast + b*H_
__global__ __launch_bounds__(256) void fc_head_flat(
    const f16* __restrict__ hlast, const f16* __restrict__ wfcT,
    const float* __restrict__ bfc, float* __restrict__ out) {
  __shared__ f16 hs[H_];
  const int b = blockIdx.x;
  const int o = threadIdx.x;
  reinterpret_cast<f16x4*>(hs)[o] =
      reinterpret_cast<const f16x4*>(hlast + (size_t)b * H_)[o];
  __syncthreads();
  float acc = bfc[o];
  const half8* wp = reinterpret_cast<const half8*>(wfcT) + o;
  const half8* hv = reinterpret_cast<const half8*>(hs);
#pragma unroll 8
  for (int c8 = 0; c8 < H_ / 8; ++c8) acc = dot8f(wp[(size_t)c8 * O_], hv[c8], acc);
  out[(size_t)b * O_ + o] = acc;
}

// ---------- tier-3: round-1 weight-streaming (3 MB ws) ----------
__global__ __launch_bounds__(1024) void rnn_f16(
    const float* __restrict__ x, const f16* __restrict__ wihT,
    const f16* __restrict__ whhT, const float* __restrict__ bih,
    const float* __restrict__ bhh, const f16* __restrict__ wfcT,
    const float* __restrict__ bfc, float* __restrict__ out) {
  __shared__ f16 hs[H_];
  __shared__ f16 xs[I_];
  const int b = blockIdx.x;
  const int j = threadIdx.x;
  const float bias = bih[j] + bhh[j];
  hs[j] = (f16)0.f;
  const half8* wih_p = reinterpret_cast<const half8*>(wihT) + j;
  const half8* whh_p = reinterpret_cast<const half8*>(whhT) + j;
  const half8* xv = reinterpret_cast<const half8*>(xs);
  const half8* hv = reinterpret_cast<const half8*>(hs);
  const float* xrow = x + (size_t)b * T_ * I_;
  for (int t = 0; t < T_; ++t) {
    if (j < I_) xs[j] = (f16)xrow[t * I_ + j];
    __syncthreads();
    float acc = bias;
#pragma unroll 8
    for (int c = 0; c < I_ / 8; ++c) acc = dot8f(wih_p[c * H_], xv[c], acc);
#pragma unroll 8
    for (int c = 0; c < H_ / 8; ++c) acc = dot8f(whh_p[c * H_], hv[c], acc);
    float hn = tanhf(acc);
    __syncthreads();
    hs[j] = (f16)hn;
  }
  __syncthreads();
  if (j < O_) {
    const half8* wfc_p = reinterpret_cast<const half8*>(wfcT) + j;
    float acc = bfc[j];
#pragma unroll 8
    for (int c = 0; c < H_ / 8; ++c) acc = dot8f(wfc_p[c * O_], hv[c], acc);
    out[(size_t)b * O_ + j] = acc;
  }
}

// ---------- tier-4: fp32, zero ws ----------
__global__ __launch_bounds__(1024) void rnn_fp32(
    const float* __restrict__ x,
    const float* __restrict__ Wih, const float* __restrict__ Whh,
    const float* __restrict__ bih, const float* __restrict__ bhh,
    const float* __restrict__ Wfc, const float* __restrict__ bfc,
    float* __restrict__ out) {
  __shared__ float hs[H_];
  __shared__ float xs[I_];
  const int b = blockIdx.x;
  const int j = threadIdx.x;
  const float bias = bih[j] + bhh[j];
  hs[j] = 0.f;
  const float4* wih_r = reinterpret_cast<const float4*>(Wih + (size_t)j * I_);
  const float4* whh_r = reinterpret_cast<const float4*>(Whh + (size_t)j * H_);
  const float4* xv = reinterpret_cast<const float4*>(xs);
  const float4* hv = reinterpret_cast<const float4*>(hs);
  const float* xrow = x + (size_t)b * T_ * I_;
  for (int t = 0; t < T_; ++t) {
    if (j < I_) xs[j] = xrow[t * I_ + j];
    __syncthreads();
    float acc = bias;
#pragma unroll 4
    for (int c = 0; c < I_ / 4; ++c) {
      float4 w = wih_r[c], v = xv[c];
      acc = fmaf(w.x, v.x, acc); acc = fmaf(w.y, v.y, acc);
      acc = fmaf(w.z, v.z, acc); acc = fmaf(w.w, v.w, acc);
    }
#pragma unroll 4
    for (int c = 0; c < H_ / 4; ++c) {
      float4 w = whh_r[c], v = hv[c];
      acc = fmaf(w.x, v.x, acc); acc = fmaf(w.y, v.y, acc);
      acc = fmaf(w.z, v.z, acc); acc = fmaf(w.w, v.w, acc);
    }
    float hn = tanhf(acc);
    __syncthreads();
    hs[j] = hn;
  }
  __syncthreads();
  if (j < O_) {
    float acc = bfc[j];
    const float4* wfc_r = reinterpret_cast<const float4*>(Wfc + (size_t)j * H_);
    for (int c = 0; c < H_ / 4; ++c) {
      float4 w = wfc_r[c], v = hv[c];
      acc = fmaf(w.x, v.x, acc); acc = fmaf(w.y, v.y, acc);
      acc = fmaf(w.z, v.z, acc); acc = fmaf(w.w, v.w, acc);
    }
    out[(size_t)b * O_ + j] = acc;
  }
}

extern "C" void kernel_launch(void* const* d_in, const int* in_sizes, int n_in,
                              void* d_out, int out_size, void* d_ws, size_t ws_size,
                              hipStream_t stream) {
  const float* x   = (const float*)d_in[0];
  const float* Wih = (const float*)d_in[1];
  const float* Whh = (const float*)d_in[2];
  const float* bih = (const float*)d_in[3];
  const float* bhh = (const float*)d_in[4];
  const float* Wfc = (const float*)d_in[5];
  const float* bfc = (const float*)d_in[6];
  float* out = (float*)d_out;

  const size_t n_whh = (size_t)H_ * H_;
  const size_t n_wih = (size_t)H_ * I_;
  const size_t n_wfc = (size_t)O_ * H_;
  const size_t n_x   = (size_t)B_ * T_ * I_;
  const size_t n_hseq = (size_t)T_ * NCLUST * MB * H_;
  const int thr = 256;

  // ---- tier 1 layout: whh | wih | wfcT | xbf | hseq  (~83 MB)
  {
    size_t off = 0;
    const size_t o_whh = off; off += n_whh;
    const size_t o_wih = off; off += n_wih;
    const size_t o_wfc = off; off += n_wfc;
    const size_t o_x   = off; off += n_x;
    const size_t o_hs  = off; off += n_hseq;
    const size_t need1 = off * sizeof(f16);

    if (ws_size >= need1) {
      f16* wsf   = (f16*)d_ws;
      f16* whh_h = wsf + o_whh;
      f16* wih_h = wsf + o_wih;
      f16* wfcT  = wsf + o_wfc;
      f16* xbf   = wsf + o_x;
      f16* hseq  = wsf + o_hs;

      const long n16 = (long)(n_hseq * sizeof(f16) / 16);
      init_hseq<<<4096, thr, 0, stream>>>((unsigned*)hseq, n16);
      cast_f16<<<(int)(n_whh / 4 / thr), thr, 0, stream>>>(Whh, whh_h, (int)(n_whh / 4));
      cast_f16<<<(int)(n_wih / 4 / thr), thr, 0, stream>>>(Wih, wih_h, (int)(n_wih / 4));
      cast_f16<<<(int)(n_x / 4 / thr), thr, 0, stream>>>(x, xbf, (int)(n_x / 4));
      convert_T8<<<(int)(n_wfc / 8 / thr), thr, 0, stream>>>(Wfc, wfcT, O_, H_);

      rnn8<<<256, thr, 0, stream>>>(whh_h, wih_h, xbf, bih, bhh, hseq);
      const f16* hlast = hseq + (size_t)(T_ - 1) * NCLUST * MB * H_;
      fc_head_flat<<<B_, O_, 0, stream>>>(hlast, wfcT, bfc, out);
      return;
    }
  }

  // ---- tier 3 (3 MB) / tier 4 (0)
  if (ws_size >= (n_wih + n_whh + n_wfc) * sizeof(f16)) {
    f16* wihT = (f16*)d_ws;
    f16* whhT = wihT + n_wih;
    f16* wfcT = whhT + n_whh;
    convert_T8<<<(int)((n_wih / 8 + thr - 1) / thr), thr, 0, stream>>>(Wih, wihT, H_, I_);
    convert_T8<<<(int)((n_whh / 8 + thr - 1) / thr), thr, 0, stream>>>(Whh, whhT, H_, H_);
    convert_T8<<<(int)((n_wfc / 8 + thr - 1) / thr), thr, 0, stream>>>(Wfc, wfcT, O_, H_);
    rnn_f16<<<B_, 1024, 0, stream>>>(x, wihT, whhT, bih, bhh, wfcT, bfc, out);
  } else {
    rnn_fp32<<<B_, 1024, 0, stream>>>(x, Wih, Whh, bih, bhh, Wfc, bfc, out);
  }
}

// Round 9
// 1601.432 us; speedup vs baseline: 1.6716x; 1.6716x over previous
//
#include <hip/hip_runtime.h>

#define B_ 64
#define T_ 512
#define I_ 256
#define H_ 1024
#define O_ 256

#define NCLUST 4
#define WPC 16        // workgroups per cluster (fat WGs)
#define MB 16         // batches per cluster
#define ROWS 64       // h-rows per WG = 4 MFMA n-tiles per wave
#define NT 4          // n-tiles per wave
#define SENT 0x7FFF7FFFu   // f16 NaN pair: tanh output can never equal this

typedef _Float16 f16;
typedef _Float16 f16x2 __attribute__((ext_vector_type(2)));
typedef _Float16 f16x4 __attribute__((ext_vector_type(4)));
typedef _Float16 half8 __attribute__((ext_vector_type(8)));
typedef float floatx4 __attribute__((ext_vector_type(4)));
typedef unsigned int uint4v __attribute__((ext_vector_type(4)));

// ---------- memory helpers ----------
// sc0 sc1: bypass L1+L2, access MALL (device coherence point) — the ONLY
// sound path for sentinel-polled data (r8 lesson: cached reads install the
// stale sentinel line; no line-granular invalidate exists).
__device__ __forceinline__ uint4v load_uc16(const void* p) {
  uint4v r;
  asm volatile("global_load_dwordx4 %0, %1, off sc0 sc1" : "=v"(r) : "v"(p));
  return r;
}
__device__ __forceinline__ void store_uc4(void* p, unsigned v) {
  asm volatile("global_store_dword %0, %1, off sc0 sc1" :: "v"(p), "v"(v) : "memory");
}
__device__ __forceinline__ void store_uc16(void* p, uint4v v) {
  asm volatile("global_store_dwordx4 %0, %1, off sc0 sc1" :: "v"(p), "v"(v) : "memory");
}
__device__ __forceinline__ unsigned pack_f16x2(float a, float b) {
  f16x2 t; t[0] = (f16)a; t[1] = (f16)b;
  return __builtin_bit_cast(unsigned, t);
}

#if __has_builtin(__builtin_amdgcn_fdot2)
__device__ __forceinline__ float dot2f(f16x2 a, f16x2 b, float c) {
  return __builtin_amdgcn_fdot2(a, b, c, false);
}
#else
__device__ __forceinline__ float dot2f(f16x2 a, f16x2 b, float c) {
  return fmaf((float)a[0], (float)b[0], fmaf((float)a[1], (float)b[1], c));
}
#endif

__device__ __forceinline__ float dot8f(half8 w, half8 v, float acc) {
  acc = dot2f(__builtin_shufflevector(w, w, 0, 1), __builtin_shufflevector(v, v, 0, 1), acc);
  acc = dot2f(__builtin_shufflevector(w, w, 2, 3), __builtin_shufflevector(v, v, 2, 3), acc);
  acc = dot2f(__builtin_shufflevector(w, w, 4, 5), __builtin_shufflevector(v, v, 4, 5), acc);
  acc = dot2f(__builtin_shufflevector(w, w, 6, 7), __builtin_shufflevector(v, v, 6, 7), acc);
  return acc;
}

// ---------- converters / init ----------
__global__ void cast_f16(const float* __restrict__ src, f16* __restrict__ dst, int n4) {
  int i = blockIdx.x * blockDim.x + threadIdx.x;
  if (i >= n4) return;
  float4 a = reinterpret_cast<const float4*>(src)[i];
  f16x4 v;
  v[0] = (f16)a.x; v[1] = (f16)a.y; v[2] = (f16)a.z; v[3] = (f16)a.w;
  reinterpret_cast<f16x4*>(dst)[i] = v;
}

__global__ void convert_T8(const float* __restrict__ src, f16* __restrict__ dst,
                           int R, int K) {
  int K8 = K >> 3;
  int total = R * K8;
  int idx = blockIdx.x * blockDim.x + threadIdx.x;
  if (idx >= total) return;
  int r = idx / K8;
  int k8 = idx - r * K8;
  const float4* s = reinterpret_cast<const float4*>(src + (size_t)r * K + (size_t)k8 * 8);
  float4 a = s[0], b = s[1];
  half8 v;
  v[0] = (f16)a.x; v[1] = (f16)a.y; v[2] = (f16)a.z; v[3] = (f16)a.w;
  v[4] = (f16)b.x; v[5] = (f16)b.y; v[6] = (f16)b.z; v[7] = (f16)b.w;
  reinterpret_cast<half8*>(dst)[(size_t)k8 * R + r] = v;
}

// sentinel-fill hseq via MALL bypass stores; re-run every launch (replay-safe)
__global__ void init_hseq(unsigned* __restrict__ p, long n16) {
  uint4v sv; sv[0] = SENT; sv[1] = SENT; sv[2] = SENT; sv[3] = SENT;
  long i = (long)blockIdx.x * blockDim.x + threadIdx.x;
  const long stride = (long)gridDim.x * blockDim.x;
  for (; i < n16; i += stride) store_uc16(p + 4 * i, sv);
}

// ---------- tier-1 recurrent kernel: fat-WG sentinel dataflow (r6 protocol) ----------
// grid 64 x 256 thr. Cluster c = wg&3 owns batches [c*16,+16); worker w = wg>>2
// (0..15) owns h rows [w*64,+64) = 4 n-tiles per wave. Per wave the A-fragment
// (16 batches x K=256 slice) is loaded ONCE and reused for 4 n-tiles -> device
// h fan-out drops 8 MB -> 2 MB per step vs r6. All h exchange via MALL
// (sc0 sc1), fire-and-forget sentinel protocol; selective packet reload.
__global__ __launch_bounds__(256) void rnn9(
    const f16* __restrict__ whh,   // [H][H] f16
    const f16* __restrict__ wih,   // [H][I] f16
    const f16* __restrict__ xbf,   // [B][T][I] f16
    const float* __restrict__ bih,
    const float* __restrict__ bhh,
    f16* __restrict__ hseq) {      // [T][NCLUST][MB][H] f16 (sentinel-filled)
  const int wg = blockIdx.x;
  const int c = wg & 3;
  const int w = wg >> 2;          // 0..15
  const int tid = threadIdx.x;
  const int wv = tid >> 6;
  const int lane = tid & 63;
  const int lr = lane & 15;
  const int kb = lane >> 4;
  const int n0 = w * ROWS;
  const int b0 = c * MB;

  // stationary B-fragments: 4 n-tiles x (8 h-chunks + 2 x-chunks) of K
  half8 bfh[NT][8];
  half8 bfx[NT][2];
#pragma unroll
  for (int nt = 0; nt < NT; ++nt) {
    const int nrow = n0 + nt * 16 + lr;
#pragma unroll
    for (int i = 0; i < 8; ++i) {
      const int k = wv * 256 + i * 32 + kb * 8;
      bfh[nt][i] = *reinterpret_cast<const half8*>(&whh[(size_t)nrow * H_ + k]);
    }
#pragma unroll
    for (int j = 0; j < 2; ++j) {
      const int k = wv * 64 + j * 32 + kb * 8;
      bfx[nt][j] = *reinterpret_cast<const half8*>(&wih[(size_t)nrow * I_ + k]);
    }
  }

  // output ownership after K-split reduce (validated): m=((lane>>4)<<2)|wv, col=lane&15
  const int m = ((lane >> 4) << 2) | wv;
  const int nl = lane & 15;
  float bias[NT];
#pragma unroll
  for (int nt = 0; nt < NT; ++nt)
    bias[nt] = bih[n0 + nt * 16 + nl] + bhh[n0 + nt * 16 + nl];

  const f16* xrow = xbf + (size_t)(b0 + lr) * T_ * I_ + wv * 64 + kb * 8;

  __shared__ floatx4 red[2][NT][4][64];   // [parity][ntile][wave][lane] = 32 KB
  const size_t CST = (size_t)NCLUST * MB * H_;
  const size_t coff = (size_t)c * MB * H_;

  for (int s = 1; s <= T_; ++s) {
    // x part (cached loads; xbf is LLC-resident)
    const f16* xs = xrow + (size_t)(s - 1) * I_;
    half8 ax0 = *reinterpret_cast<const half8*>(xs);
    half8 ax1 = *reinterpret_cast<const half8*>(xs + 32);

    floatx4 acc[NT];
#pragma unroll
    for (int nt = 0; nt < NT; ++nt) {
      floatx4 z = {0.f, 0.f, 0.f, 0.f};
      z = __builtin_amdgcn_mfma_f32_16x16x32_f16(ax0, bfx[nt][0], z, 0, 0, 0);
      z = __builtin_amdgcn_mfma_f32_16x16x32_f16(ax1, bfx[nt][1], z, 0, 0, 0);
      acc[nt] = z;
    }

    if (s > 1) {
      const f16* hr = hseq + (size_t)(s - 2) * CST + coff;  // h[s-1]
      uint4v af[8];
      unsigned need = 0xFFu;   // per-lane mask of still-sentinel packets
      int g = 0;
      for (;;) {
        // merged poll+load, selective reload, MALL path only
#pragma unroll
        for (int i = 0; i < 8; ++i) {
          if (need & (1u << i)) {
            af[i] = load_uc16(&hr[(size_t)lr * H_ + wv * 256 + i * 32 + kb * 8]);
          }
        }
        asm volatile("s_waitcnt vmcnt(0)" ::: "memory");
        unsigned nn = 0u;
#pragma unroll
        for (int i = 0; i < 8; ++i) {
          if (need & (1u << i)) {
            unsigned bad = (unsigned)(af[i][0] == SENT) | (unsigned)(af[i][1] == SENT) |
                           (unsigned)(af[i][2] == SENT) | (unsigned)(af[i][3] == SENT);
            nn |= bad << i;
          }
        }
        need = nn;
        if (__all(need == 0u)) break;
        if (++g > (1 << 12)) break;   // fail-fast valve (validation catches)
        __builtin_amdgcn_s_sleep(1);
      }
      __builtin_amdgcn_sched_barrier(0);
      // A-fragment reused across all 4 n-tiles (the fan-out win)
#pragma unroll
      for (int i = 0; i < 8; ++i) {
        half8 a = __builtin_bit_cast(half8, af[i]);
#pragma unroll
        for (int nt = 0; nt < NT; ++nt) {
          acc[nt] = __builtin_amdgcn_mfma_f32_16x16x32_f16(a, bfh[nt][i], acc[nt], 0, 0, 0);
        }
      }
    }

    // K-split reduce (parity-buffered: one barrier per step)
    const int pr = s & 1;
#pragma unroll
    for (int nt = 0; nt < NT; ++nt) red[pr][nt][wv][lane] = acc[nt];
    __syncthreads();

    f16* hw = hseq + (size_t)(s - 1) * CST + coff;
#pragma unroll
    for (int nt = 0; nt < NT; ++nt) {
      float v = red[pr][nt][0][lane][wv] + red[pr][nt][1][lane][wv] +
                red[pr][nt][2][lane][wv] + red[pr][nt][3][lane][wv] + bias[nt];
      float hn = tanhf(v);
      float po = __shfl_xor(hn, 1);
      if (!(lane & 1)) {
        store_uc4(&hw[(size_t)m * H_ + n0 + nt * 16 + nl], pack_f16x2(hn, po));
      }
    }
    // fire-and-forget: data IS the flag.
  }
}

// FC head over flat h_last rows: row b at hlast + b*H_
__global__ __launch_bounds__(256) void fc_head_flat(
    const f16* __restrict__ hlast, const f16* __restrict__ wfcT,
    const float* __restrict__ bfc, float* __restrict__ out) {
  __shared__ f16 hs[H_];
  const int b = blockIdx.x;
  const int o = threadIdx.x;
  reinterpret_cast<f16x4*>(hs)[o] =
      reinterpret_cast<const f16x4*>(hlast + (size_t)b * H_)[o];
  __syncthreads();
  float acc = bfc[o];
  const half8* wp = reinterpret_cast<const half8*>(wfcT) + o;
  const half8* hv = reinterpret_cast<const half8*>(hs);
#pragma unroll 8
  for (int c8 = 0; c8 < H_ / 8; ++c8) acc = dot8f(wp[(size_t)c8 * O_], hv[c8], acc);
  out[(size_t)b * O_ + o] = acc;
}

// ---------- tier-3: round-1 weight-streaming (3 MB ws) ----------
__global__ __launch_bounds__(1024) void rnn_f16(
    const float* __restrict__ x, const f16* __restrict__ wihT,
    const f16* __restrict__ whhT, const float* __restrict__ bih,
    const float* __restrict__ bhh, const f16* __restrict__ wfcT,
    const float* __restrict__ bfc, float* __restrict__ out) {
  __shared__ f16 hs[H_];
  __shared__ f16 xs[I_];
  const int b = blockIdx.x;
  const int j = threadIdx.x;
  const float bias = bih[j] + bhh[j];
  hs[j] = (f16)0.f;
  const half8* wih_p = reinterpret_cast<const half8*>(wihT) + j;
  const half8* whh_p = reinterpret_cast<const half8*>(whhT) + j;
  const half8* xv = reinterpret_cast<const half8*>(xs);
  const half8* hv = reinterpret_cast<const half8*>(hs);
  const float* xrow = x + (size_t)b * T_ * I_;
  for (int t = 0; t < T_; ++t) {
    if (j < I_) xs[j] = (f16)xrow[t * I_ + j];
    __syncthreads();
    float acc = bias;
#pragma unroll 8
    for (int c = 0; c < I_ / 8; ++c) acc = dot8f(wih_p[c * H_], xv[c], acc);
#pragma unroll 8
    for (int c = 0; c < H_ / 8; ++c) acc = dot8f(whh_p[c * H_], hv[c], acc);
    float hn = tanhf(acc);
    __syncthreads();
    hs[j] = (f16)hn;
  }
  __syncthreads();
  if (j < O_) {
    const half8* wfc_p = reinterpret_cast<const half8*>(wfcT) + j;
    float acc = bfc[j];
#pragma unroll 8
    for (int c = 0; c < H_ / 8; ++c) acc = dot8f(wfc_p[c * O_], hv[c], acc);
    out[(size_t)b * O_ + j] = acc;
  }
}

// ---------- tier-4: fp32, zero ws ----------
__global__ __launch_bounds__(1024) void rnn_fp32(
    const float* __restrict__ x,
    const float* __restrict__ Wih, const float* __restrict__ Whh,
    const float* __restrict__ bih, const float* __restrict__ bhh,
    const float* __restrict__ Wfc, const float* __restrict__ bfc,
    float* __restrict__ out) {
  __shared__ float hs[H_];
  __shared__ float xs[I_];
  const int b = blockIdx.x;
  const int j = threadIdx.x;
  const float bias = bih[j] + bhh[j];
  hs[j] = 0.f;
  const float4* wih_r = reinterpret_cast<const float4*>(Wih + (size_t)j * I_);
  const float4* whh_r = reinterpret_cast<const float4*>(Whh + (size_t)j * H_);
  const float4* xv = reinterpret_cast<const float4*>(xs);
  const float4* hv = reinterpret_cast<const float4*>(hs);
  const float* xrow = x + (size_t)b * T_ * I_;
  for (int t = 0; t < T_; ++t) {
    if (j < I_) xs[j] = xrow[t * I_ + j];
    __syncthreads();
    float acc = bias;
#pragma unroll 4
    for (int c = 0; c < I_ / 4; ++c) {
      float4 w = wih_r[c], v = xv[c];
      acc = fmaf(w.x, v.x, acc); acc = fmaf(w.y, v.y, acc);
      acc = fmaf(w.z, v.z, acc); acc = fmaf(w.w, v.w, acc);
    }
#pragma unroll 4
    for (int c = 0; c < H_ / 4; ++c) {
      float4 w = whh_r[c], v = hv[c];
      acc = fmaf(w.x, v.x, acc); acc = fmaf(w.y, v.y, acc);
      acc = fmaf(w.z, v.z, acc); acc = fmaf(w.w, v.w, acc);
    }
    float hn = tanhf(acc);
    __syncthreads();
    hs[j] = hn;
  }
  __syncthreads();
  if (j < O_) {
    float acc = bfc[j];
    const float4* wfc_r = reinterpret_cast<const float4*>(Wfc + (size_t)j * H_);
    for (int c = 0; c < H_ / 4; ++c) {
      float4 w = wfc_r[c], v = hv[c];
      acc = fmaf(w.x, v.x, acc); acc = fmaf(w.y, v.y, acc);
      acc = fmaf(w.z, v.z, acc); acc = fmaf(w.w, v.w, acc);
    }
    out[(size_t)b * O_ + j] = acc;
  }
}

extern "C" void kernel_launch(void* const* d_in, const int* in_sizes, int n_in,
                              void* d_out, int out_size, void* d_ws, size_t ws_size,
                              hipStream_t stream) {
  const float* x   = (const float*)d_in[0];
  const float* Wih = (const float*)d_in[1];
  const float* Whh = (const float*)d_in[2];
  const float* bih = (const float*)d_in[3];
  const float* bhh = (const float*)d_in[4];
  const float* Wfc = (const float*)d_in[5];
  const float* bfc = (const float*)d_in[6];
  float* out = (float*)d_out;

  const size_t n_whh = (size_t)H_ * H_;
  const size_t n_wih = (size_t)H_ * I_;
  const size_t n_wfc = (size_t)O_ * H_;
  const size_t n_x   = (size_t)B_ * T_ * I_;
  const size_t n_hseq = (size_t)T_ * NCLUST * MB * H_;
  const int thr = 256;

  // ---- tier 1 layout: whh | wih | wfcT | xbf | hseq  (~83 MB)
  {
    size_t off = 0;
    const size_t o_whh = off; off += n_whh;
    const size_t o_wih = off; off += n_wih;
    const size_t o_wfc = off; off += n_wfc;
    const size_t o_x   = off; off += n_x;
    const size_t o_hs  = off; off += n_hseq;
    const size_t need1 = off * sizeof(f16);

    if (ws_size >= need1) {
      f16* wsf   = (f16*)d_ws;
      f16* whh_h = wsf + o_whh;
      f16* wih_h = wsf + o_wih;
      f16* wfcT  = wsf + o_wfc;
      f16* xbf   = wsf + o_x;
      f16* hseq  = wsf + o_hs;

      const long n16 = (long)(n_hseq * sizeof(f16) / 16);
      init_hseq<<<4096, thr, 0, stream>>>((unsigned*)hseq, n16);
      cast_f16<<<(int)(n_whh / 4 / thr), thr, 0, stream>>>(Whh, whh_h, (int)(n_whh / 4));
      cast_f16<<<(int)(n_wih / 4 / thr), thr, 0, stream>>>(Wih, wih_h, (int)(n_wih / 4));
      cast_f16<<<(int)(n_x / 4 / thr), thr, 0, stream>>>(x, xbf, (int)(n_x / 4));
      convert_T8<<<(int)(n_wfc / 8 / thr), thr, 0, stream>>>(Wfc, wfcT, O_, H_);

      rnn9<<<NCLUST * WPC, thr, 0, stream>>>(whh_h, wih_h, xbf, bih, bhh, hseq);
      const f16* hlast = hseq + (size_t)(T_ - 1) * NCLUST * MB * H_;
      fc_head_flat<<<B_, O_, 0, stream>>>(hlast, wfcT, bfc, out);
      return;
    }
  }

  // ---- tier 3 (3 MB) / tier 4 (0)
  if (ws_size >= (n_wih + n_whh + n_wfc) * sizeof(f16)) {
    f16* wihT = (f16*)d_ws;
    f16* whhT = wihT + n_wih;
    f16* wfcT = whhT + n_whh;
    convert_T8<<<(int)((n_wih / 8 + thr - 1) / thr), thr, 0, stream>>>(Wih, wihT, H_, I_);
    convert_T8<<<(int)((n_whh / 8 + thr - 1) / thr), thr, 0, stream>>>(Whh, whhT, H_, H_);
    convert_T8<<<(int)((n_wfc / 8 + thr - 1) / thr), thr, 0, stream>>>(Wfc, wfcT, O_, H_);
    rnn_f16<<<B_, 1024, 0, stream>>>(x, wihT, whhT, bih, bhh, wfcT, bfc, out);
  } else {
    rnn_fp32<<<B_, 1024, 0, stream>>>(x, Wih, Whh, bih, bhh, Wfc, bfc, out);
  }
}